// Round 8
// baseline (270.430 us; speedup 1.0000x reference)
//
#include <hip/hip_runtime.h>

// EMA Vector Quantizer — R8: 2-deep tile-pipelined MFMA (MFMA(t) || argmin(t-1) || prefetch(t+1)),
// triple-buffered LDS chunks staged 2 ahead, split stats.
// z: (32,64,64,64) fp32; w: (1024,64) fp32.
// Out flat: q (8388608) | loss (1) | commitment (1) | count (1024) | sum (65536)

#define HWsz   4096
#define Dd     64
#define Kk     1024
#define NB     32
#define NTOT   131072
#define QSIZE  (NTOT * Dd)
#define BETA_C 0.25f
#define DIST_BLOCKS 1024

typedef float  f32x4  __attribute__((ext_vector_type(4)));
typedef short  bf16x8 __attribute__((ext_vector_type(8)));

#define MF(a, b, c) __builtin_amdgcn_mfma_f32_16x16x32_bf16((a), (b), (c), 0, 0, 0)
#define Z4 ((f32x4){0.f, 0.f, 0.f, 0.f})

__device__ __forceinline__ unsigned short f2bf(float f) {
    unsigned u = __float_as_uint(f);
    u += 0x7FFF + ((u >> 16) & 1);
    return (unsigned short)(u >> 16);
}
__device__ __forceinline__ float bf2f(unsigned short b) {
    return __uint_as_float(((unsigned)b) << 16);
}

__device__ __forceinline__ void stage16(const void* g, void* lds) {
    __builtin_amdgcn_global_load_lds(
        (const __attribute__((address_space(1))) unsigned int*)g,
        (__attribute__((address_space(3))) unsigned int*)lds, 16, 0, 0);
}

// ---------------- prep: c2 norms + codebook bf16 hi/lo split (B-frag layout) ----
__global__ __launch_bounds__(256) void vq_prep(const float* __restrict__ w,
                                               float* __restrict__ c2,
                                               unsigned short* __restrict__ whi,
                                               unsigned short* __restrict__ wlo) {
    int t = blockIdx.x * 256 + threadIdx.x;           // 65536 threads
    int k = t >> 6, d = t & 63;
    float v = w[t];
    unsigned short hb = f2bf(v);
    unsigned short lb = f2bf(v - bf2f(hb));
    int ctile = k >> 4, col = k & 15;
    int s = d >> 5, kg = (d >> 3) & 3, j = d & 7;
    int idx = (((ctile * 2 + s) * 64) + kg * 16 + col) * 8 + j;
    whi[idx] = hb; wlo[idx] = lb;

    if (t < Kk) {
        const float4* c4 = reinterpret_cast<const float4*>(w + t * Dd);
        float s0 = 0.f, s1 = 0.f, s2 = 0.f, s3 = 0.f;
#pragma unroll
        for (int q = 0; q < 16; ++q) {
            float4 cq = c4[q];
            s0 = fmaf(cq.x, cq.x, s0); s1 = fmaf(cq.y, cq.y, s1);
            s2 = fmaf(cq.z, cq.z, s2); s3 = fmaf(cq.w, cq.w, s3);
        }
        c2[t] = (s0 + s1) + (s2 + s3);
    }
}

// ---------------- phase 1: pipelined distances + argmin ----------------
// 1024 blocks x 4 waves; each wave owns 32 rows (M=2 row-tiles).
// LDS: 3 x 16 KB chunk buffers (chunk = 4 ct-tiles; tile = 4KB = [wh0|wh1|wl0|wl1]).
__global__ __launch_bounds__(256) void vq_dist(const float* __restrict__ z,
                                               const float* __restrict__ w,
                                               const float* __restrict__ c2,
                                               const unsigned short* __restrict__ whi,
                                               const unsigned short* __restrict__ wlo,
                                               float* __restrict__ out,
                                               float* __restrict__ commit_ws,
                                               int* __restrict__ idx_ws) {
    const int lane = threadIdx.x & 63;
    const int wid  = threadIdx.x >> 6;                 // 0..3
    const int b    = blockIdx.x >> 5;
    const int hwb  = (blockIdx.x & 31) * 128 + wid * 32;
    const int col  = lane & 15;
    const int kg   = lane >> 4;

    __shared__ unsigned short lbuf[3][8192];           // 3 x 16 KB

    // ---- A fragments, M=2 row-tiles (hi/lo bf16 split) ----
    bf16x8 zhi[2][2], zlo[2][2];
#pragma unroll
    for (int m = 0; m < 2; ++m) {
        const float* zbase = z + (size_t)b * (Dd * HWsz) + (hwb + m * 16) + col;
#pragma unroll
        for (int s = 0; s < 2; ++s) {
            bf16x8 h, l;
#pragma unroll
            for (int j = 0; j < 8; ++j) {
                float zz = zbase[(size_t)(32 * s + kg * 8 + j) * HWsz];
                unsigned short hb = f2bf(zz);
                unsigned short lb = f2bf(zz - bf2f(hb));
                h[j] = (short)hb; l[j] = (short)lb;
            }
            zhi[m][s] = h; zlo[m][s] = l;
        }
    }

    const char* ghi = (const char*)whi;
    const char* glo = (const char*)wlo;
    // wave wid stages tile wid of chunk C into buffer P (4 x 1KB slots)
#define STAGE(C, P)                                                               \
    {                                                                             \
        int tb = ((C) * 4 + wid) * 2;                                             \
        stage16(ghi + (size_t)(tb + 0) * 1024 + lane * 16, (P) + wid * 2048 + 0 * 512); \
        stage16(ghi + (size_t)(tb + 1) * 1024 + lane * 16, (P) + wid * 2048 + 1 * 512); \
        stage16(glo + (size_t)(tb + 0) * 1024 + lane * 16, (P) + wid * 2048 + 2 * 512); \
        stage16(glo + (size_t)(tb + 1) * 1024 + lane * 16, (P) + wid * 2048 + 3 * 512); \
    }

    float best[2][4];
    int   bk[2][4];
#pragma unroll
    for (int m = 0; m < 2; ++m)
#pragma unroll
        for (int r = 0; r < 4; ++r) { best[m][r] = 3.4e38f; bk[m][r] = 0; }

    unsigned short* p0 = lbuf[0];
    unsigned short* p1 = lbuf[1];
    unsigned short* p2 = lbuf[2];

    STAGE(0, p0);
    STAGE(1, p1);
    __syncthreads();                                   // drains vmcnt -> chunks 0,1 ready

    // pipeline regs: set A = current tile frags, set B = next
    bf16x8 hA0, hA1, lA0, lA1, hB0, hB1, lB0, lB1;
    float  cvA, cvB = 0.f;
    f32x4  accA[2][2], accB[2][2];

    hA0 = *(const bf16x8*)(p0 + 0 * 512 + lane * 8);
    hA1 = *(const bf16x8*)(p0 + 1 * 512 + lane * 8);
    lA0 = *(const bf16x8*)(p0 + 2 * 512 + lane * 8);
    lA1 = *(const bf16x8*)(p0 + 3 * 512 + lane * 8);
    cvA = c2[col];

    // step: compute tile TG (frags H*,L*, cv CV) into AW; prefetch TG+1 into N*; argmin TG-1 from AR
#define TSTEP(H0, H1, L0, L1, CV, NH0, NH1, NL0, NL1, NCV, AW, AR, TG, NBUF, NTT, DOPF, DOAM) \
    {                                                                             \
        float cvp = NCV; /* cv of tile TG-1 (old set contents) */                 \
        if (DOPF) {                                                               \
            NH0 = *(const bf16x8*)((NBUF) + (NTT) * 2048 + 0 * 512 + lane * 8);   \
            NH1 = *(const bf16x8*)((NBUF) + (NTT) * 2048 + 1 * 512 + lane * 8);   \
            NL0 = *(const bf16x8*)((NBUF) + (NTT) * 2048 + 2 * 512 + lane * 8);   \
            NL1 = *(const bf16x8*)((NBUF) + (NTT) * 2048 + 3 * 512 + lane * 8);   \
            NCV = c2[((TG) + 1) * 16 + col];                                      \
        }                                                                         \
        AW[0][0] = MF(zhi[0][0], H0, Z4);       AW[1][0] = MF(zhi[1][0], H0, Z4); \
        AW[0][1] = MF(zhi[0][1], H1, Z4);       AW[1][1] = MF(zhi[1][1], H1, Z4); \
        AW[0][0] = MF(zhi[0][0], L0, AW[0][0]); AW[1][0] = MF(zhi[1][0], L0, AW[1][0]); \
        AW[0][1] = MF(zhi[0][1], L1, AW[0][1]); AW[1][1] = MF(zhi[1][1], L1, AW[1][1]); \
        AW[0][0] = MF(zlo[0][0], H0, AW[0][0]); AW[1][0] = MF(zlo[1][0], H0, AW[1][0]); \
        AW[0][1] = MF(zlo[0][1], H1, AW[0][1]); AW[1][1] = MF(zlo[1][1], H1, AW[1][1]); \
        if (DOAM) {                                                               \
            int kcp = ((TG) - 1) * 16 + col;                                      \
            _Pragma("unroll")                                                     \
            for (int m = 0; m < 2; ++m)                                           \
                _Pragma("unroll")                                                 \
                for (int r = 0; r < 4; ++r) {                                     \
                    float s = fmaf(-2.f, AR[m][0][r] + AR[m][1][r], cvp);         \
                    if (s < best[m][r]) { best[m][r] = s; bk[m][r] = kcp; }       \
                }                                                                 \
        }                                                                         \
    }

    for (int c = 0; c < 16; ++c) {
        const int t0 = c * 4;
        if (c) __syncthreads();                        // chunk c+1 staged-complete; c-1 readers done
        if (c < 14) STAGE(c + 2, p2);
        TSTEP(hA0, hA1, lA0, lA1, cvA, hB0, hB1, lB0, lB1, cvB, accA, accB, t0 + 0, p0, 1, true, (c > 0));
        TSTEP(hB0, hB1, lB0, lB1, cvB, hA0, hA1, lA0, lA1, cvA, accB, accA, t0 + 1, p0, 2, true, true);
        TSTEP(hA0, hA1, lA0, lA1, cvA, hB0, hB1, lB0, lB1, cvB, accA, accB, t0 + 2, p0, 3, true, true);
        TSTEP(hB0, hB1, lB0, lB1, cvB, hA0, hA1, lA0, lA1, cvA, accB, accA, t0 + 3, p1, 0, (c < 15), true);
        unsigned short* tmp = p0; p0 = p1; p1 = p2; p2 = tmp;
    }
    // final argmin: tile 63 (odd step -> accB, cvB)
    {
        int kcp = 63 * 16 + col;
#pragma unroll
        for (int m = 0; m < 2; ++m)
#pragma unroll
            for (int r = 0; r < 4; ++r) {
                float s = fmaf(-2.f, accB[m][0][r] + accB[m][1][r], cvB);
                if (s < best[m][r]) { best[m][r] = s; bk[m][r] = kcp; }
            }
    }

    // ---- merge argmin across 16 code-column lanes (first-index tie-break) ----
#pragma unroll
    for (int off = 1; off < 16; off <<= 1) {
#pragma unroll
        for (int m = 0; m < 2; ++m)
#pragma unroll
            for (int r = 0; r < 4; ++r) {
                float ob = __shfl_xor(best[m][r], off, 64);
                int   ok = __shfl_xor(bk[m][r],   off, 64);
                if (ob < best[m][r] || (ob == best[m][r] && ok < bk[m][r])) {
                    best[m][r] = ob; bk[m][r] = ok;
                }
            }
    }

    // ---- epilogue ----
    float commit = 0.f;
    const int srcl = (col >> 2) << 4;
    const int rsel = col & 3;
#pragma unroll
    for (int m = 0; m < 2; ++m) {
        int c0 = __shfl(bk[m][0], srcl, 64);
        int c1 = __shfl(bk[m][1], srcl, 64);
        int c2r = __shfl(bk[m][2], srcl, 64);
        int c3 = __shfl(bk[m][3], srcl, 64);
        int mybk = (rsel == 0) ? c0 : (rsel == 1) ? c1 : (rsel == 2) ? c2r : c3;

        const int hw0 = hwb + m * 16;
        if (lane < 16) idx_ws[(size_t)b * HWsz + hw0 + col] = mybk;

        float* qbase = out + (size_t)b * (Dd * HWsz) + hw0 + col;
#pragma unroll
        for (int s = 0; s < 2; ++s) {
            const float4* cw = reinterpret_cast<const float4*>(w + mybk * Dd + 32 * s + kg * 8);
            float4 pp0 = cw[0], pp1 = cw[1];
            float cbv[8] = {pp0.x, pp0.y, pp0.z, pp0.w, pp1.x, pp1.y, pp1.z, pp1.w};
#pragma unroll
            for (int j = 0; j < 8; ++j) {
                int   d  = 32 * s + kg * 8 + j;
                float zz = bf2f((unsigned short)zhi[m][s][j]) +
                           bf2f((unsigned short)zlo[m][s][j]);
                float cc = cbv[j];
                qbase[(size_t)d * HWsz] = zz + (cc - zz);
                float dd = zz - cc;
                commit = fmaf(dd, dd, commit);
            }
        }
    }

#pragma unroll
    for (int off = 32; off > 0; off >>= 1) commit += __shfl_down(commit, off, 64);

    __shared__ float red[4];
    if (lane == 0) red[wid] = commit;
    __syncthreads();
    if (threadIdx.x == 0)
        commit_ws[blockIdx.x] = (red[0] + red[1]) + (red[2] + red[3]);
}

// ---------------- phase 2: per-(b, d-pair, hw-split) LDS accumulation ----------
__global__ __launch_bounds__(256) void vq_stats(const float* __restrict__ z,
                                                const int* __restrict__ idx_ws,
                                                float* __restrict__ psum,
                                                float* __restrict__ pcnt,
                                                int nsplit) {
    const int q  = blockIdx.x % nsplit;
    const int t_ = blockIdx.x / nsplit;
    const int dp = t_ & 31;
    const int b  = t_ >> 5;
    const int d0 = dp * 2;
    const bool docnt = (dp == 0);

    __shared__ float acc0[Kk], acc1[Kk], cnt[Kk];
    for (int i = threadIdx.x; i < Kk; i += 256) { acc0[i] = 0.f; acc1[i] = 0.f; cnt[i] = 0.f; }
    __syncthreads();

    const int pos4 = (HWsz / 4) / nsplit;
    const int4*   ip  = reinterpret_cast<const int4*>(idx_ws + (size_t)b * HWsz);
    const float4* zp0 = reinterpret_cast<const float4*>(z + ((size_t)b * Dd + d0) * HWsz);
    const float4* zp1 = reinterpret_cast<const float4*>(z + ((size_t)b * Dd + d0 + 1) * HWsz);
    for (int c = threadIdx.x; c < pos4; c += 256) {
        const int c4 = q * pos4 + c;
        int4   k4 = ip[c4];
        float4 v0 = zp0[c4];
        float4 v1 = zp1[c4];
        atomicAdd(&acc0[k4.x], v0.x); atomicAdd(&acc0[k4.y], v0.y);
        atomicAdd(&acc0[k4.z], v0.z); atomicAdd(&acc0[k4.w], v0.w);
        atomicAdd(&acc1[k4.x], v1.x); atomicAdd(&acc1[k4.y], v1.y);
        atomicAdd(&acc1[k4.z], v1.z); atomicAdd(&acc1[k4.w], v1.w);
        if (docnt) {
            atomicAdd(&cnt[k4.x], 1.f); atomicAdd(&cnt[k4.y], 1.f);
            atomicAdd(&cnt[k4.z], 1.f); atomicAdd(&cnt[k4.w], 1.f);
        }
    }
    __syncthreads();

    float* po = psum + ((size_t)(b * nsplit + q) * Dd + d0) * Kk;
    for (int i = threadIdx.x; i < Kk; i += 256) { po[i] = acc0[i]; po[Kk + i] = acc1[i]; }
    if (docnt) {
        float* pc = pcnt + (size_t)(b * nsplit + q) * Kk;
        for (int i = threadIdx.x; i < Kk; i += 256) pc[i] = cnt[i];
    }
}

// ---------------- phase 3: reduce partials + losses ----------------
__global__ __launch_bounds__(256) void vq_reduce(const float* __restrict__ psum,
                                                 const float* __restrict__ pcnt,
                                                 const float* __restrict__ commit_ws,
                                                 float* __restrict__ out,
                                                 int nparts) {
    int t = blockIdx.x * 256 + threadIdx.x;   // 65536 threads
    int k = t & 1023, d = t >> 10;
    float s = 0.f;
    for (int p = 0; p < nparts; ++p)
        s += psum[((size_t)p * Dd + d) * Kk + k];
    out[QSIZE + 2 + Kk + (size_t)k * Dd + d] = s;
    if (t < Kk) {
        float c = 0.f;
        for (int p = 0; p < nparts; ++p) c += pcnt[(size_t)p * Kk + t];
        out[QSIZE + 2 + t] = c;
    }

    if (blockIdx.x == 0) {
        float cs = 0.f;
        for (int i = threadIdx.x; i < DIST_BLOCKS; i += 256) cs += commit_ws[i];
#pragma unroll
        for (int off = 32; off > 0; off >>= 1) cs += __shfl_down(cs, off, 64);
        __shared__ float r2[4];
        const int lane = threadIdx.x & 63, wid = threadIdx.x >> 6;
        if (lane == 0) r2[wid] = cs;
        __syncthreads();
        if (threadIdx.x == 0) {
            float c = ((r2[0] + r2[1]) + (r2[2] + r2[3])) / (float)QSIZE;
            out[QSIZE]     = BETA_C * c;
            out[QSIZE + 1] = c;
        }
    }
}

extern "C" void kernel_launch(void* const* d_in, const int* in_sizes, int n_in,
                              void* d_out, int out_size, void* d_ws, size_t ws_size,
                              hipStream_t stream) {
    const float* z = (const float*)d_in[0];
    const float* w = (const float*)d_in[1];
    float* out = (float*)d_out;

    // ws layout (float offsets):
    // commit 0..1023 | c2 1024..2047 | whi (65536 us) | wlo (65536 us) |
    // idx (131072 int) | pcnt (NB*nsplit*1024) | psum (NB*nsplit*64*1024)
    float* commit_ws = (float*)d_ws;
    float* c2        = (float*)d_ws + 1024;
    unsigned short* whi = (unsigned short*)((float*)d_ws + 2048);
    unsigned short* wlo = whi + (Kk * Dd);
    int*   idx_ws = (int*)(wlo + (Kk * Dd));
    float* pcnt   = (float*)(idx_ws + NTOT);

    const size_t fixed_floats = 2048 + 65536 + 131072;
    int nsplit = 2;
    size_t need2 = (fixed_floats + (size_t)NB * 2 * Kk + (size_t)NB * 2 * Dd * Kk) * 4;
    if (ws_size < need2) nsplit = 1;
    float* psum = pcnt + (size_t)NB * nsplit * Kk;

    vq_prep<<<(Kk * Dd) / 256, 256, 0, stream>>>(w, c2, whi, wlo);
    vq_dist<<<DIST_BLOCKS, 256, 0, stream>>>(z, w, c2, whi, wlo, out, commit_ws, idx_ws);
    vq_stats<<<NB * 32 * nsplit, 256, 0, stream>>>(z, idx_ws, psum, pcnt, nsplit);
    vq_reduce<<<(Kk * Dd) / 256, 256, 0, stream>>>(psum, pcnt, commit_ws, out, NB * nsplit);
}

// Round 9
// 243.899 us; speedup vs baseline: 1.1088x; 1.1088x over previous
//
#include <hip/hip_runtime.h>

// EMA Vector Quantizer — R9: 32x32x16 MFMA, barrier-free L2-streamed B-frags,
// unroll-2 alternating register sets, immediate-offset addressing.
// z: (32,64,64,64) fp32; w: (1024,64) fp32.
// Out flat: q (8388608) | loss (1) | commitment (1) | count (1024) | sum (65536)

#define HWsz   4096
#define Dd     64
#define Kk     1024
#define NB     32
#define NTOT   131072
#define QSIZE  (NTOT * Dd)
#define BETA_C 0.25f
#define DIST_BLOCKS 1024

typedef float  f32x16 __attribute__((ext_vector_type(16)));
typedef short  bf16x8 __attribute__((ext_vector_type(8)));

#define MF32(a, b, c) __builtin_amdgcn_mfma_f32_32x32x16_bf16((a), (b), (c), 0, 0, 0)

__device__ __forceinline__ unsigned short f2bf(float f) {
    unsigned u = __float_as_uint(f);
    u += 0x7FFF + ((u >> 16) & 1);
    return (unsigned short)(u >> 16);
}
__device__ __forceinline__ float bf2f(unsigned short b) {
    return __uint_as_float(((unsigned)b) << 16);
}

// ---------------- prep: c2 norms + codebook bf16 hi/lo split (32x32 B-frag) ----
// B-frag for mfma_f32_32x32x16_bf16: lane l holds B[k=(l>>5)*8+j][col=l&31].
// Record for (code-tile ct, kstep s): idx = ((ct*4+s)*64 + lane)*8 + j.
__global__ __launch_bounds__(256) void vq_prep(const float* __restrict__ w,
                                               float* __restrict__ c2,
                                               unsigned short* __restrict__ whi,
                                               unsigned short* __restrict__ wlo) {
    int t = blockIdx.x * 256 + threadIdx.x;           // 65536 threads
    int k = t >> 6, d = t & 63;
    float v = w[t];
    unsigned short hb = f2bf(v);
    unsigned short lb = f2bf(v - bf2f(hb));
    int ct = k >> 5, col = k & 31;
    int s = d >> 4, half = (d >> 3) & 1, j = d & 7;
    int lane = half * 32 + col;
    int idx = (((ct * 4 + s) * 64) + lane) * 8 + j;
    whi[idx] = hb; wlo[idx] = lb;

    if (t < Kk) {
        const float4* c4 = reinterpret_cast<const float4*>(w + t * Dd);
        float s0 = 0.f, s1 = 0.f, s2 = 0.f, s3 = 0.f;
#pragma unroll
        for (int q = 0; q < 16; ++q) {
            float4 cq = c4[q];
            s0 = fmaf(cq.x, cq.x, s0); s1 = fmaf(cq.y, cq.y, s1);
            s2 = fmaf(cq.z, cq.z, s2); s3 = fmaf(cq.w, cq.w, s3);
        }
        c2[t] = (s0 + s1) + (s2 + s3);
    }
}

// ---------------- phase 1: distances, argmin, q, commitment, idx ----------------
// 1024 blocks x 4 waves; each wave owns 32 rows via one 32x32 MFMA tile set.
__global__ __launch_bounds__(256) void vq_dist(const float* __restrict__ z,
                                               const float* __restrict__ w,
                                               const float* __restrict__ c2,
                                               const unsigned short* __restrict__ whi,
                                               const unsigned short* __restrict__ wlo,
                                               float* __restrict__ out,
                                               float* __restrict__ commit_ws,
                                               int* __restrict__ idx_ws) {
    const int lane = threadIdx.x & 63;
    const int wid  = threadIdx.x >> 6;
    const int b    = blockIdx.x >> 5;
    const int hwb  = (blockIdx.x & 31) * 128 + wid * 32;
    const int c32  = lane & 31;                        // code col / z row
    const int dh   = (lane >> 5) * 8;                  // k-half offset

    // ---- A fragments: 32 rows x K=64, hi/lo bf16 split ----
    const float* zbase = z + (size_t)b * (Dd * HWsz) + hwb + c32;
    bf16x8 zhi[4], zlo[4];
#pragma unroll
    for (int s = 0; s < 4; ++s) {
        bf16x8 h, l;
#pragma unroll
        for (int j = 0; j < 8; ++j) {
            float zz = zbase[(size_t)(16 * s + dh + j) * HWsz];
            unsigned short hb = f2bf(zz);
            unsigned short lb = f2bf(zz - bf2f(hb));
            h[j] = (short)hb; l[j] = (short)lb;
        }
        zhi[s] = h; zlo[s] = l;
    }

    float best[16];
    int   bk[16];
#pragma unroll
    for (int r = 0; r < 16; ++r) { best[r] = 3.4e38f; bk[r] = 0; }

    // running pointers (advanced 8 KB per pair-iteration); imm offsets 0..3072
    const bf16x8* pha = reinterpret_cast<const bf16x8*>(whi) + lane;          // even tiles
    const bf16x8* pla = reinterpret_cast<const bf16x8*>(wlo) + lane;
    const bf16x8* phb = pha + 256;                                            // odd tiles
    const bf16x8* plb = pla + 256;
    const float*  cvp = c2 + c32;

#define LOADB(H0, H1, H2, H3, L0, L1, L2, L3, CV, PH, PL, CTI)   \
    {                                                            \
        H0 = (PH)[0 * 64]; H1 = (PH)[1 * 64];                    \
        H2 = (PH)[2 * 64]; H3 = (PH)[3 * 64];                    \
        L0 = (PL)[0 * 64]; L1 = (PL)[1 * 64];                    \
        L2 = (PL)[2 * 64]; L3 = (PL)[3 * 64];                    \
        CV = cvp[(CTI) * 32];                                    \
    }

#define COMPUTE(H0, H1, H2, H3, L0, L1, L2, L3, CV, CT)                        \
    {                                                                          \
        f32x16 p = {0.f,0.f,0.f,0.f,0.f,0.f,0.f,0.f,0.f,0.f,0.f,0.f,0.f,0.f,0.f,0.f}; \
        f32x16 q = {0.f,0.f,0.f,0.f,0.f,0.f,0.f,0.f,0.f,0.f,0.f,0.f,0.f,0.f,0.f,0.f}; \
        p = MF32(zhi[0], H0, p);  q = MF32(zhi[2], H2, q);                     \
        p = MF32(zhi[1], H1, p);  q = MF32(zhi[3], H3, q);                     \
        p = MF32(zlo[0], H0, p);  q = MF32(zlo[2], H2, q);                     \
        p = MF32(zlo[1], H1, p);  q = MF32(zlo[3], H3, q);                     \
        p = MF32(zhi[0], L0, p);  q = MF32(zhi[2], L2, q);                     \
        p = MF32(zhi[1], L1, p);  q = MF32(zhi[3], L3, q);                     \
        const int kc = (CT) * 32 + c32;                                        \
        _Pragma("unroll")                                                      \
        for (int r = 0; r < 16; ++r) {                                         \
            float sc = fmaf(-2.f, p[r] + q[r], CV);                            \
            if (sc < best[r]) { best[r] = sc; bk[r] = kc; }                    \
        }                                                                      \
    }

    bf16x8 aH0, aH1, aH2, aH3, aL0, aL1, aL2, aL3;
    bf16x8 bH0, bH1, bH2, bH3, bL0, bL1, bL2, bL3;
    float  acv, bcv;

    LOADB(aH0, aH1, aH2, aH3, aL0, aL1, aL2, aL3, acv, pha, pla, 0);

    for (int it = 0; it < 16; ++it) {
        const int ct = it * 2;
        LOADB(bH0, bH1, bH2, bH3, bL0, bL1, bL2, bL3, bcv, phb, plb, ct + 1);
        COMPUTE(aH0, aH1, aH2, aH3, aL0, aL1, aL2, aL3, acv, ct);
        pha += 512; pla += 512;                         // advance 2 tiles (8 KB)
        if (it < 15)
            LOADB(aH0, aH1, aH2, aH3, aL0, aL1, aL2, aL3, acv, pha, pla, ct + 2);
        COMPUTE(bH0, bH1, bH2, bH3, bL0, bL1, bL2, bL3, bcv, ct + 1);
        phb += 512; plb += 512;
    }

    // ---- merge argmin across the 32 code-column lanes of each half ----
#pragma unroll
    for (int off = 1; off < 32; off <<= 1) {
#pragma unroll
        for (int r = 0; r < 16; ++r) {
            float ob = __shfl_xor(best[r], off, 64);
            int   ok = __shfl_xor(bk[r],   off, 64);
            if (ob < best[r] || (ob == best[r] && ok < bk[r])) {
                best[r] = ob; bk[r] = ok;
            }
        }
    }

    // ---- extract winner for my row (row = lane&31) ----
    // row r: half = (r>>2)&1, reg = (r&3) + 4*(r>>3)
    const int hi5   = ((lane >> 2) & 1) << 5;
    const int myreg = (lane & 3) + (((lane >> 3) & 3) << 2);
    int mybk = 0;
#pragma unroll
    for (int re = 0; re < 16; ++re) {
        int t = __shfl(bk[re], hi5, 64);
        if (re == myreg) mybk = t;
    }

    if (lane < 32) idx_ws[(size_t)b * HWsz + hwb + lane] = mybk;

    // ---- gather codeword, q write, commitment ----
    float* qbase = out + (size_t)b * (Dd * HWsz) + hwb + c32;
    float commit = 0.f;
#pragma unroll
    for (int s = 0; s < 4; ++s) {
        const float4* cw = reinterpret_cast<const float4*>(w + mybk * Dd + 16 * s + dh);
        float4 p0 = cw[0], p1 = cw[1];
        float cbv[8] = {p0.x, p0.y, p0.z, p0.w, p1.x, p1.y, p1.z, p1.w};
#pragma unroll
        for (int j = 0; j < 8; ++j) {
            int   d  = 16 * s + dh + j;
            float zz = bf2f((unsigned short)zhi[s][j]) + bf2f((unsigned short)zlo[s][j]);
            float cc = cbv[j];
            qbase[(size_t)d * HWsz] = zz + (cc - zz);
            float dd = zz - cc;
            commit = fmaf(dd, dd, commit);
        }
    }

#pragma unroll
    for (int off = 32; off > 0; off >>= 1) commit += __shfl_down(commit, off, 64);

    __shared__ float red[4];
    if (lane == 0) red[wid] = commit;
    __syncthreads();
    if (threadIdx.x == 0)
        commit_ws[blockIdx.x] = (red[0] + red[1]) + (red[2] + red[3]);
}

// ---------------- phase 2: per-(b, d-pair) LDS accumulation (R7 form) ----------
__global__ __launch_bounds__(256) void vq_stats(const float* __restrict__ z,
                                                const int* __restrict__ idx_ws,
                                                float* __restrict__ psum,
                                                float* __restrict__ pcnt) {
    const int b  = blockIdx.x >> 5;
    const int dp = blockIdx.x & 31;
    const int d0 = dp * 2;
    const bool docnt = (dp == 0);

    __shared__ float acc0[Kk], acc1[Kk], cnt[Kk];
    for (int i = threadIdx.x; i < Kk; i += 256) { acc0[i] = 0.f; acc1[i] = 0.f; cnt[i] = 0.f; }
    __syncthreads();

    const int4*   ip  = reinterpret_cast<const int4*>(idx_ws + (size_t)b * HWsz);
    const float4* zp0 = reinterpret_cast<const float4*>(z + ((size_t)b * Dd + d0) * HWsz);
    const float4* zp1 = reinterpret_cast<const float4*>(z + ((size_t)b * Dd + d0 + 1) * HWsz);
#pragma unroll
    for (int it = 0; it < 4; ++it) {
        int c4 = it * 256 + threadIdx.x;
        int4   k4 = ip[c4];
        float4 v0 = zp0[c4];
        float4 v1 = zp1[c4];
        atomicAdd(&acc0[k4.x], v0.x); atomicAdd(&acc0[k4.y], v0.y);
        atomicAdd(&acc0[k4.z], v0.z); atomicAdd(&acc0[k4.w], v0.w);
        atomicAdd(&acc1[k4.x], v1.x); atomicAdd(&acc1[k4.y], v1.y);
        atomicAdd(&acc1[k4.z], v1.z); atomicAdd(&acc1[k4.w], v1.w);
        if (docnt) {
            atomicAdd(&cnt[k4.x], 1.f); atomicAdd(&cnt[k4.y], 1.f);
            atomicAdd(&cnt[k4.z], 1.f); atomicAdd(&cnt[k4.w], 1.f);
        }
    }
    __syncthreads();

    float* po = psum + ((size_t)b * Dd + d0) * Kk;
    for (int i = threadIdx.x; i < Kk; i += 256) { po[i] = acc0[i]; po[Kk + i] = acc1[i]; }
    if (docnt) {
        float* pc = pcnt + (size_t)b * Kk;
        for (int i = threadIdx.x; i < Kk; i += 256) pc[i] = cnt[i];
    }
}

// ---------------- phase 3: reduce partials over batch + losses ----------------
__global__ __launch_bounds__(256) void vq_reduce(const float* __restrict__ psum,
                                                 const float* __restrict__ pcnt,
                                                 const float* __restrict__ commit_ws,
                                                 float* __restrict__ out) {
    int t = blockIdx.x * 256 + threadIdx.x;   // 65536 threads
    int k = t & 1023, d = t >> 10;
    float s = 0.f;
#pragma unroll
    for (int b = 0; b < NB; ++b)
        s += psum[((size_t)b * Dd + d) * Kk + k];
    out[QSIZE + 2 + Kk + (size_t)k * Dd + d] = s;
    if (t < Kk) {
        float c = 0.f;
#pragma unroll
        for (int b = 0; b < NB; ++b) c += pcnt[((size_t)b << 10) + t];
        out[QSIZE + 2 + t] = c;
    }

    if (blockIdx.x == 0) {
        float cs = 0.f;
        for (int i = threadIdx.x; i < DIST_BLOCKS; i += 256) cs += commit_ws[i];
#pragma unroll
        for (int off = 32; off > 0; off >>= 1) cs += __shfl_down(cs, off, 64);
        __shared__ float r2[4];
        const int lane = threadIdx.x & 63, wid = threadIdx.x >> 6;
        if (lane == 0) r2[wid] = cs;
        __syncthreads();
        if (threadIdx.x == 0) {
            float c = ((r2[0] + r2[1]) + (r2[2] + r2[3])) / (float)QSIZE;
            out[QSIZE]     = BETA_C * c;
            out[QSIZE + 1] = c;
        }
    }
}

extern "C" void kernel_launch(void* const* d_in, const int* in_sizes, int n_in,
                              void* d_out, int out_size, void* d_ws, size_t ws_size,
                              hipStream_t stream) {
    const float* z = (const float*)d_in[0];
    const float* w = (const float*)d_in[1];
    float* out = (float*)d_out;

    // ws layout (float offsets):
    // commit 0..1023 | c2 1024..2047 | whi (65536 us) | wlo (65536 us) |
    // idx (131072 int) | pcnt (32*1024) | psum (32*64*1024)
    float* commit_ws = (float*)d_ws;
    float* c2        = (float*)d_ws + 1024;
    unsigned short* whi = (unsigned short*)((float*)d_ws + 2048);
    unsigned short* wlo = whi + (Kk * Dd);
    int*   idx_ws = (int*)(wlo + (Kk * Dd));
    float* pcnt   = (float*)(idx_ws + NTOT);
    float* psum   = pcnt + (size_t)NB * Kk;

    vq_prep<<<(Kk * Dd) / 256, 256, 0, stream>>>(w, c2, whi, wlo);
    vq_dist<<<DIST_BLOCKS, 256, 0, stream>>>(z, w, c2, whi, wlo, out, commit_ws, idx_ws);
    vq_stats<<<NB * 32, 256, 0, stream>>>(z, idx_ws, psum, pcnt);
    vq_reduce<<<(Kk * Dd) / 256, 256, 0, stream>>>(psum, pcnt, commit_ws, out);
}

// Round 10
// 216.199 us; speedup vs baseline: 1.2508x; 1.1281x over previous
//
#include <hip/hip_runtime.h>

// EMA Vector Quantizer — R10: TRANSPOSED dataflow. Codes resident in registers
// (MFMA A-operand), z streams through shared LDS (B-operand). c2 folded into a
// 5th MFMA k-step. 4 code-families; per-row partials merged by epilogue kernel.
// z: (32,64,64,64) fp32; w: (1024,64) fp32.
// Out flat: q (8388608) | loss (1) | commitment (1) | count (1024) | sum (65536)

#define HWsz   4096
#define Dd     64
#define Kk     1024
#define NB     32
#define NTOT   131072
#define QSIZE  (NTOT * Dd)
#define BETA_C 0.25f
#define NFAM   4
#define ROWS_PER_BLK 512
#define NT     16            // 512 rows / 32 per tile
#define EPI_BLOCKS 512

typedef float  f32x16 __attribute__((ext_vector_type(16)));
typedef short  bf16x8 __attribute__((ext_vector_type(8)));
typedef unsigned short ushort_t;
typedef unsigned long long u64;

#define MF32(a, b, c) __builtin_amdgcn_mfma_f32_32x32x16_bf16((a), (b), (c), 0, 0, 0)

__device__ __forceinline__ ushort_t f2bf(float f) {
    unsigned u = __float_as_uint(f);
    u += 0x7FFF + ((u >> 16) & 1);
    return (ushort_t)(u >> 16);
}
__device__ __forceinline__ float bf2f(ushort_t b) {
    return __uint_as_float(((unsigned)b) << 16);
}
__device__ __forceinline__ u64 pack4(ushort_t a, ushort_t b, ushort_t c, ushort_t d) {
    return (u64)a | ((u64)b << 16) | ((u64)c << 32) | ((u64)d << 48);
}

// ---- prep: codebook records as 32x32 MFMA A-frags, 5 k-steps (step 4 = -c2/2 dim) ----
// record idx for (group ct, step s): ((ct*5+s)*64 + lane)*8 + j
// steps 0-3: lane l holds code ct*32+(l&31), dims s*16+(l>>5)*8+j (hi & lo split)
// step 4:    dims 64..79: value -0.5*||c||^2 at dim 64 (hi only), else 0
__global__ __launch_bounds__(256) void vq_prep(const float* __restrict__ w,
                                               ushort_t* __restrict__ whi,
                                               ushort_t* __restrict__ wlo) {
    int t = blockIdx.x * 256 + threadIdx.x;           // 81920 threads
    if (t < Kk * Dd) {
        int k = t >> 6, d = t & 63;
        float v = w[t];
        ushort_t hb = f2bf(v);
        ushort_t lb = f2bf(v - bf2f(hb));
        int ct = k >> 5;
        int s = d >> 4, h = (d >> 3) & 1, j = d & 7;
        int lane = h * 32 + (k & 31);
        int idx = (((ct * 5 + s) * 64) + lane) * 8 + j;
        whi[idx] = hb; wlo[idx] = lb;
    } else {
        int u = t - Kk * Dd;                           // 16384 step-4 slots
        int ct = u >> 9, slot = u & 511;
        int ln = slot >> 3, j = slot & 7;
        ushort_t hb = 0;
        if (ln < 32 && j == 0) {
            const float4* c4 = reinterpret_cast<const float4*>(w + (ct * 32 + ln) * Dd);
            float s0 = 0.f, s1 = 0.f, s2 = 0.f, s3 = 0.f;
#pragma unroll
            for (int q = 0; q < 16; ++q) {
                float4 cq = c4[q];
                s0 = fmaf(cq.x, cq.x, s0); s1 = fmaf(cq.y, cq.y, s1);
                s2 = fmaf(cq.z, cq.z, s2); s3 = fmaf(cq.w, cq.w, s3);
            }
            hb = f2bf(-0.5f * ((s0 + s1) + (s2 + s3)));
        }
        int idx = (((ct * 5 + 4) * 64) + ln) * 8 + j;
        whi[idx] = hb; wlo[idx] = 0;
    }
}

// ---- phase 1: code-resident scorer -----------------------------------------
// grid = NFAM * 256 blocks x 512 thr (8 waves). Wave w owns codes fam*256+w*32..+31.
// Per tile (32 rows): z staged in LDS as bf16 hi/lo (swizzled), all waves share.
__global__ __launch_bounds__(512) void vq_dist(const float* __restrict__ z,
                                               const ushort_t* __restrict__ whi,
                                               const ushort_t* __restrict__ wlo,
                                               float* __restrict__ famS,
                                               int* __restrict__ famK) {
    const int tid  = threadIdx.x;
    const int lane = tid & 63;
    const int wid  = tid >> 6;                         // 0..7
    const int fam  = blockIdx.x >> 8;
    const int rb   = blockIdx.x & 255;
    const int b    = rb >> 3;
    const int hw0  = (rb & 7) * ROWS_PER_BLK;
    const int hi5  = lane >> 5;
    const int ct   = fam * 8 + wid;
    const int grp0 = ct * 32;

    // ---- resident code A-frags ----
    const bf16x8* PH = reinterpret_cast<const bf16x8*>(whi) + (size_t)(ct * 5) * 64 + lane;
    const bf16x8* PL = reinterpret_cast<const bf16x8*>(wlo) + (size_t)(ct * 5) * 64 + lane;
    bf16x8 ch0 = PH[0], ch1 = PH[64], ch2 = PH[128], ch3 = PH[192], cx = PH[256];
    bf16x8 cl0 = PL[0], cl1 = PL[64], cl2 = PL[128], cl3 = PL[192];

    bf16x8 zext = (bf16x8){0, 0, 0, 0, 0, 0, 0, 0};
    if (lane < 32) zext[0] = (short)0x3F80;            // 1.0 bf16 at dim 64

    __shared__ ushort_t zbH[2][2048];                  // [buf][32 rows x 64 dims]
    __shared__ ushort_t zbL[2][2048];
    __shared__ float mrgS[2][8][32];
    __shared__ int   mrgK[2][8][32];

    // stage-thread mapping: row = tid&31, d-quad = tid>>5 (0..15)
    const int srow = tid & 31;
    const int d0   = (tid >> 5) * 4;
    const int woff = ((srow * 128 + d0 * 2) ^ ((srow & 7) << 4));
    const float* zsrc = z + ((size_t)(b * Dd + d0)) * HWsz + hw0 + srow;

#define ISSUE(TT, R0, R1, R2, R3)                              \
    { const float* p_ = zsrc + (TT) * 32;                      \
      R0 = p_[0]; R1 = p_[HWsz]; R2 = p_[2 * HWsz]; R3 = p_[3 * HWsz]; }

#define WRITEB(TT, R0, R1, R2, R3)                                          \
    { ushort_t h0_ = f2bf(R0), h1_ = f2bf(R1), h2_ = f2bf(R2), h3_ = f2bf(R3); \
      ushort_t l0_ = f2bf(R0 - bf2f(h0_)), l1_ = f2bf(R1 - bf2f(h1_));      \
      ushort_t l2_ = f2bf(R2 - bf2f(h2_)), l3_ = f2bf(R3 - bf2f(h3_));      \
      *(u64*)((char*)&zbH[(TT) & 1][0] + woff) = pack4(h0_, h1_, h2_, h3_); \
      *(u64*)((char*)&zbL[(TT) & 1][0] + woff) = pack4(l0_, l1_, l2_, l3_); }

    // read-address bases (swizzled per s inside loop)
    const int roBase = (lane & 31) * 128 + hi5 * 16;
    const int roSwz  = ((lane & 31) & 7) << 4;

    float Ra0, Ra1, Ra2, Ra3, Rb0, Rb1, Rb2, Rb3;

    // prologue: tile 0 staged synchronously; tile 1 loads in flight
    ISSUE(0, Ra0, Ra1, Ra2, Ra3);
    WRITEB(0, Ra0, Ra1, Ra2, Ra3);
    ISSUE(1, Rb0, Rb1, Rb2, Rb3);
    __syncthreads();

#pragma unroll 2
    for (int t = 0; t < NT; ++t) {
        const int cur = t & 1;
        const bool even = (cur == 0);
        if (t < NT - 2) {
            if (even) { ISSUE(t + 2, Ra0, Ra1, Ra2, Ra3); }
            else      { ISSUE(t + 2, Rb0, Rb1, Rb2, Rb3); }
        }

        // ---- compute tile t ----
        const char* hp = (const char*)&zbH[cur][0];
        const char* lp = (const char*)&zbL[cur][0];
        bf16x8 zh0 = *(const bf16x8*)(hp + ((roBase +  0) ^ roSwz));
        bf16x8 zh1 = *(const bf16x8*)(hp + ((roBase + 32) ^ roSwz));
        bf16x8 zh2 = *(const bf16x8*)(hp + ((roBase + 64) ^ roSwz));
        bf16x8 zh3 = *(const bf16x8*)(hp + ((roBase + 96) ^ roSwz));
        bf16x8 zl0 = *(const bf16x8*)(lp + ((roBase +  0) ^ roSwz));
        bf16x8 zl1 = *(const bf16x8*)(lp + ((roBase + 32) ^ roSwz));
        bf16x8 zl2 = *(const bf16x8*)(lp + ((roBase + 64) ^ roSwz));
        bf16x8 zl3 = *(const bf16x8*)(lp + ((roBase + 96) ^ roSwz));

        f32x16 acc = {0.f,0.f,0.f,0.f,0.f,0.f,0.f,0.f,0.f,0.f,0.f,0.f,0.f,0.f,0.f,0.f};
        acc = MF32(ch0, zh0, acc);  acc = MF32(ch0, zl0, acc);  acc = MF32(cl0, zh0, acc);
        acc = MF32(ch1, zh1, acc);  acc = MF32(ch1, zl1, acc);  acc = MF32(cl1, zh1, acc);
        acc = MF32(ch2, zh2, acc);  acc = MF32(ch2, zl2, acc);  acc = MF32(cl2, zh2, acc);
        acc = MF32(ch3, zh3, acc);  acc = MF32(ch3, zl3, acc);  acc = MF32(cl3, zh3, acc);
        acc = MF32(cx, zext, acc);                       // + (-c2/2)

        // per-lane argmax over its 16 codes (reg asc == code asc -> strict >)
        float bs = acc[0];
        int   bkk = grp0 + 4 * hi5;
#pragma unroll
        for (int r = 1; r < 16; ++r) {
            int cd = grp0 + (r & 3) + 8 * (r >> 2) + 4 * hi5;
            if (acc[r] > bs) { bs = acc[r]; bkk = cd; }
        }
        // merge the two lane-halves (same z-row, other 16 codes)
        float os = __shfl_xor(bs, 32, 64);
        int   ok = __shfl_xor(bkk, 32, 64);
        if (os > bs || (os == bs && ok < bkk)) { bs = os; bkk = ok; }
        if (lane < 32) { mrgS[cur][wid][lane] = bs; mrgK[cur][wid][lane] = bkk; }

        // ---- stage tile t+1 (loads issued last iter) ----
        if (t < NT - 1) {
            if (even) { WRITEB(t + 1, Rb0, Rb1, Rb2, Rb3); }
            else      { WRITEB(t + 1, Ra0, Ra1, Ra2, Ra3); }
        }
        __syncthreads();

        // ---- wave 0: merge 8 groups for tile t, write family partial ----
        if (wid == 0 && lane < 32) {
            float ms = mrgS[cur][0][lane];
            int   mk = mrgK[cur][0][lane];
#pragma unroll
            for (int g = 1; g < 8; ++g) {
                float gs = mrgS[cur][g][lane];
                int   gk = mrgK[cur][g][lane];
                if (gs > ms) { ms = gs; mk = gk; }      // groups asc = codes asc
            }
            int row = b * HWsz + hw0 + t * 32 + lane;
            famS[(size_t)fam * NTOT + row] = ms;
            famK[(size_t)fam * NTOT + row] = mk;
        }
    }
#undef ISSUE
#undef WRITEB
}

// ---- epilogue: merge families, q write, idx, commitment --------------------
__global__ __launch_bounds__(256) void vq_epi(const float* __restrict__ z,
                                              const float* __restrict__ w,
                                              const float* __restrict__ famS,
                                              const int* __restrict__ famK,
                                              float* __restrict__ out,
                                              int* __restrict__ idx_ws,
                                              float* __restrict__ commit_ws) {
    const int row = blockIdx.x * 256 + threadIdx.x;
    const int b = row >> 12, hw = row & 4095;

    float bs = famS[row];
    int   bkk = famK[row];
#pragma unroll
    for (int f = 1; f < NFAM; ++f) {
        float s2 = famS[(size_t)f * NTOT + row];
        int   k2 = famK[(size_t)f * NTOT + row];
        if (s2 > bs) { bs = s2; bkk = k2; }             // fams asc = codes asc
    }
    idx_ws[row] = bkk;

    const float* zr = z + (size_t)b * (Dd * HWsz) + hw;
    float* qr = out + (size_t)b * (Dd * HWsz) + hw;
    const float4* cw = reinterpret_cast<const float4*>(w + (size_t)bkk * Dd);
    float commit = 0.f;
#pragma unroll
    for (int c4 = 0; c4 < 16; ++c4) {
        float4 cc = cw[c4];
        float cv[4] = {cc.x, cc.y, cc.z, cc.w};
#pragma unroll
        for (int i = 0; i < 4; ++i) {
            int d = c4 * 4 + i;
            float zz = zr[(size_t)d * HWsz];
            qr[(size_t)d * HWsz] = zz + (cv[i] - zz);   // reference straight-through form
            float dd = zz - cv[i];
            commit = fmaf(dd, dd, commit);
        }
    }

#pragma unroll
    for (int off = 32; off > 0; off >>= 1) commit += __shfl_down(commit, off, 64);
    __shared__ float red[4];
    const int lane = threadIdx.x & 63, wv = threadIdx.x >> 6;
    if (lane == 0) red[wv] = commit;
    __syncthreads();
    if (threadIdx.x == 0)
        commit_ws[blockIdx.x] = (red[0] + red[1]) + (red[2] + red[3]);
}

// ---- stats: per-(b, d-pair) LDS accumulation (atomic-free out) -------------
__global__ __launch_bounds__(256) void vq_stats(const float* __restrict__ z,
                                                const int* __restrict__ idx_ws,
                                                float* __restrict__ psum,
                                                float* __restrict__ pcnt) {
    const int b  = blockIdx.x >> 5;
    const int dp = blockIdx.x & 31;
    const int d0 = dp * 2;
    const bool docnt = (dp == 0);

    __shared__ float acc0[Kk], acc1[Kk], cnt[Kk];
    for (int i = threadIdx.x; i < Kk; i += 256) { acc0[i] = 0.f; acc1[i] = 0.f; cnt[i] = 0.f; }
    __syncthreads();

    const int4*   ip  = reinterpret_cast<const int4*>(idx_ws + (size_t)b * HWsz);
    const float4* zp0 = reinterpret_cast<const float4*>(z + ((size_t)b * Dd + d0) * HWsz);
    const float4* zp1 = reinterpret_cast<const float4*>(z + ((size_t)b * Dd + d0 + 1) * HWsz);
#pragma unroll
    for (int it = 0; it < 4; ++it) {
        int c4 = it * 256 + threadIdx.x;
        int4   k4 = ip[c4];
        float4 v0 = zp0[c4];
        float4 v1 = zp1[c4];
        atomicAdd(&acc0[k4.x], v0.x); atomicAdd(&acc0[k4.y], v0.y);
        atomicAdd(&acc0[k4.z], v0.z); atomicAdd(&acc0[k4.w], v0.w);
        atomicAdd(&acc1[k4.x], v1.x); atomicAdd(&acc1[k4.y], v1.y);
        atomicAdd(&acc1[k4.z], v1.z); atomicAdd(&acc1[k4.w], v1.w);
        if (docnt) {
            atomicAdd(&cnt[k4.x], 1.f); atomicAdd(&cnt[k4.y], 1.f);
            atomicAdd(&cnt[k4.z], 1.f); atomicAdd(&cnt[k4.w], 1.f);
        }
    }
    __syncthreads();

    float* po = psum + ((size_t)b * Dd + d0) * Kk;
    for (int i = threadIdx.x; i < Kk; i += 256) { po[i] = acc0[i]; po[Kk + i] = acc1[i]; }
    if (docnt) {
        float* pc = pcnt + (size_t)b * Kk;
        for (int i = threadIdx.x; i < Kk; i += 256) pc[i] = cnt[i];
    }
}

// ---- reduce: batch partials + losses ---------------------------------------
__global__ __launch_bounds__(256) void vq_reduce(const float* __restrict__ psum,
                                                 const float* __restrict__ pcnt,
                                                 const float* __restrict__ commit_ws,
                                                 float* __restrict__ out) {
    int t = blockIdx.x * 256 + threadIdx.x;   // 65536 threads
    int k = t & 1023, d = t >> 10;
    float s = 0.f;
#pragma unroll
    for (int b = 0; b < NB; ++b)
        s += psum[((size_t)b * Dd + d) * Kk + k];
    out[QSIZE + 2 + Kk + (size_t)k * Dd + d] = s;
    if (t < Kk) {
        float c = 0.f;
#pragma unroll
        for (int b = 0; b < NB; ++b) c += pcnt[((size_t)b << 10) + t];
        out[QSIZE + 2 + t] = c;
    }

    if (blockIdx.x == 0) {
        float cs = 0.f;
        for (int i = threadIdx.x; i < EPI_BLOCKS; i += 256) cs += commit_ws[i];
#pragma unroll
        for (int off = 32; off > 0; off >>= 1) cs += __shfl_down(cs, off, 64);
        __shared__ float r2[4];
        const int lane = threadIdx.x & 63, wv = threadIdx.x >> 6;
        if (lane == 0) r2[wv] = cs;
        __syncthreads();
        if (threadIdx.x == 0) {
            float c = ((r2[0] + r2[1]) + (r2[2] + r2[3])) / (float)QSIZE;
            out[QSIZE]     = BETA_C * c;
            out[QSIZE + 1] = c;
        }
    }
}

extern "C" void kernel_launch(void* const* d_in, const int* in_sizes, int n_in,
                              void* d_out, int out_size, void* d_ws, size_t ws_size,
                              hipStream_t stream) {
    const float* z = (const float*)d_in[0];
    const float* w = (const float*)d_in[1];
    float* out = (float*)d_out;

    // ws layout (float offsets):
    float* commit_ws = (float*)d_ws;                        // 512 (pad 1024)
    float* famS      = (float*)d_ws + 1024;                 // 524288
    int*   famK      = (int*)((float*)d_ws + 1024 + 524288);// 524288
    ushort_t* whi    = (ushort_t*)((float*)d_ws + 1024 + 2 * 524288);  // 81920 us
    ushort_t* wlo    = whi + 81920;                         // 81920 us
    int*   idx_ws    = (int*)(wlo + 81920);                 // 131072
    float* pcnt      = (float*)(idx_ws + NTOT);             // 32768
    float* psum      = pcnt + (size_t)NB * Kk;              // 2097152

    vq_prep<<<(Kk * Dd + 16384) / 256, 256, 0, stream>>>(w, whi, wlo);
    vq_dist<<<NFAM * 256, 512, 0, stream>>>(z, whi, wlo, famS, famK);
    vq_epi<<<EPI_BLOCKS, 256, 0, stream>>>(z, w, famS, famK, out, idx_ws, commit_ws);
    vq_stats<<<NB * 32, 256, 0, stream>>>(z, idx_ws, psum, pcnt);
    vq_reduce<<<(Kk * Dd) / 256, 256, 0, stream>>>(psum, pcnt, commit_ws, out);
}